// Round 1
// 850.724 us; speedup vs baseline: 1.0004x; 1.0004x over previous
//
#include <hip/hip_runtime.h>
#include <hip/hip_bf16.h>

#define B_ROWS 1024
#define F_FLD  160000
#define D_DIM  16
#define NKB    (F_FLD / 32)        // 5000 K-blocks of 32 cols
#define NSTAT  (D_DIM + 1)         // 16 ev + cacc
#define ACC_N  (B_ROWS * NSTAT)    // 17408
#define CCOLS  6400                // cols per block chunk
#define NGRP   (CCOLS / 256)       // 25 ballot groups per chunk
#define KBC    (CCOLS / 32)        // 200 K-blocks per chunk
#define NCHUNK (F_FLD / CCOLS)     // 25
#define ROWS_B 32                  // rows per block (R6: 16 -> 32, halves embB refetch)
#define ROWBLK (B_ROWS / ROWS_B)   // 32 row-blocks
#define WAVES  8                   // 512 threads

typedef __attribute__((ext_vector_type(8))) short bf16x8;
typedef __attribute__((ext_vector_type(4))) float f32x4;

static __device__ inline unsigned short f2bf(float x) {
    __hip_bfloat16 h = __float2bfloat16(x);
    union { __hip_bfloat16 h; unsigned short s; } u; u.h = h; return u.s;
}

// Expand 8 mask bits -> 8 bf16 (1.0/0.0) in A-fragment register order.
// (verbatim from R4/R5, passing with absmax = bf16 noise)
static __device__ inline bf16x8 expand8(unsigned b) {
    union { unsigned u[4]; bf16x8 v; } r;
    r.u[0] = ((b        & 1u) * 0x3F80u) | (((b >> 1) & 1u) * 0x3F800000u);
    r.u[1] = (((b >> 2) & 1u) * 0x3F80u) | (((b >> 3) & 1u) * 0x3F800000u);
    r.u[2] = (((b >> 4) & 1u) * 0x3F80u) | (((b >> 5) & 1u) * 0x3F800000u);
    r.u[3] = (((b >> 6) & 1u) * 0x3F80u) | (((b >> 7) & 1u) * 0x3F800000u);
    return r.v;
}

// Pack emb -> B-frag bf16 (embB[kb][lane][j] = emb[kb*32+4j+q][n], q=lane>>4,
// n=lane&15) and c -> broadcast-B (cB2c[kb][q][j] = bias[f]-0.5||emb[f]||^2,
// f=kb*32+4j+q), computing the row norms in-register via 16-lane butterfly.
// Also zeroes acc (ws is poisoned 0xAA every call).
__global__ __launch_bounds__(256) void fm_pack(const float* __restrict__ emb,
                                               const float* __restrict__ bias,
                                               unsigned short* __restrict__ embB,
                                               unsigned short* __restrict__ cB2c,
                                               float* __restrict__ acc) {
    const int tid = threadIdx.x;
    const int kb = blockIdx.x * 4 + (tid >> 6);
    const int l = tid & 63, q = l >> 4, n = l & 15;

    float e[8];
    union { unsigned short s[8]; uint4 u; } v;
#pragma unroll
    for (int j = 0; j < 8; ++j) {
        int f = kb * 32 + 4 * j + q;
        e[j] = emb[(size_t)f * D_DIM + n];
        v.s[j] = f2bf(e[j]);
    }
    *(uint4*)(embB + ((size_t)kb * 64 + l) * 8) = v.u;

    union { unsigned short s[8]; uint4 u; } w;
#pragma unroll
    for (int j = 0; j < 8; ++j) {
        float s = e[j] * e[j];                    // reduce over n (16 lanes)
        s += __shfl_xor(s, 1);
        s += __shfl_xor(s, 2);
        s += __shfl_xor(s, 4);
        s += __shfl_xor(s, 8);
        int f = kb * 32 + 4 * j + q;
        w.s[j] = f2bf((n == 0 ? bias[f] : 0.0f) - 0.5f * s);
    }
    if (n == 0) *(uint4*)(cB2c + ((size_t)kb * 4 + q) * 8) = w.u;

    int gid = blockIdx.x * 256 + tid;
    if (gid < ACC_N) acc[gid] = 0.0f;
}

// Main: block = 32 rows x 6400 cols. R6 changes vs R5:
//  - grid(rowblock, chunk) with rowblock FASTEST: linear-consecutive blocks
//    share a chunk -> each XCD's L2 holds only ~2 chunks of embB (was: all
//    25 chunks thrashing 5.12 MB through a 4 MB L2 -> 327 MB L3/HBM refetch).
//  - ROWS_B 16 -> 32: two A-fragments (rows n, n+16) share ONE eB load per
//    K-block -> total embB demand halves to 164 MB; 4 MFMAs/iter.
// Theory: fm_main was ~210 us at 3.05 TB/s *including* ~327 MB of embB
// refetch; the pure-x floor is 655 MB / ~6 TB/s ~= 110 us. Predict ~125-150.
__global__ __launch_bounds__(512, 6) void fm_main(const int* __restrict__ x,
                                                  const unsigned short* __restrict__ embB,
                                                  const unsigned short* __restrict__ cB2c,
                                                  float* __restrict__ acc) {
    __shared__ unsigned long long msk[NGRP][ROWS_B][4];   // 25.6 KB
    __shared__ float red[WAVES][ROWS_B][NSTAT];           // 17.4 KB

    const int tid = threadIdx.x;
    const int w = tid >> 6, l = tid & 63;
    const int q = l >> 4, n = l & 15;
    const int rowbase = blockIdx.x * ROWS_B;   // rowblock = fastest grid dim
    const int c0 = blockIdx.y * CCOLS;         // chunk    = slow grid dim

    // ---- stage: wave w -> rows 4w..4w+3; each row read as one sequential
    // 25.6 KB stream (bit l of word j_w at group g <-> col g*256 + 4l + j_w)
#pragma unroll
    for (int rr = 0; rr < 4; ++rr) {
        const int rloc = 4 * w + rr;
        const int4* xp = (const int4*)(x + (size_t)(rowbase + rloc) * F_FLD + c0) + l;
        for (int g0 = 0; g0 < NGRP; g0 += 5) {
            int4 v[5];
#pragma unroll
            for (int k = 0; k < 5; ++k) v[k] = xp[(size_t)(g0 + k) * 64];
#pragma unroll
            for (int k = 0; k < 5; ++k) {
                unsigned long long m0 = __ballot(v[k].x > 0);
                unsigned long long m1 = __ballot(v[k].y > 0);
                unsigned long long m2 = __ballot(v[k].z > 0);
                unsigned long long m3 = __ballot(v[k].w > 0);
                if (l == 0) {
                    msk[g0 + k][rloc][0] = m0; msk[g0 + k][rloc][1] = m1;
                    msk[g0 + k][rloc][2] = m2; msk[g0 + k][rloc][3] = m3;
                }
            }
        }
    }
    __syncthreads();

    // ---- compute: wave w owns K-blocks w*25 .. w*25+24; one eB load feeds
    // both row-halves (rows 0-15 via A0, rows 16-31 via A1).
    f32x4 aev0 = {0.f, 0.f, 0.f, 0.f}, ac0 = {0.f, 0.f, 0.f, 0.f};
    f32x4 aev1 = {0.f, 0.f, 0.f, 0.f}, ac1 = {0.f, 0.f, 0.f, 0.f};
    const uint4* eB = (const uint4*)embB;
    const uint4* cB = (const uint4*)cB2c;
    const int kbg0 = blockIdx.y * KBC;

#pragma unroll 2
    for (int t = 0; t < KBC / WAVES; ++t) {
        const int kb = w * (KBC / WAVES) + t;        // 0..199 within chunk
        const int g = kb >> 3, byt = kb & 7;
        // A byte: bits j of byte `byt` of word q, row n  (verified mapping:
        // col kb*32 + 4j + q  ==  bit (byt*8+j) of word q at group g)
        unsigned long long mv0 = msk[g][n][q];
        unsigned long long mv1 = msk[g][n + 16][q];
        unsigned b0 = (unsigned)(mv0 >> (8 * byt)) & 0xFFu;
        unsigned b1 = (unsigned)(mv1 >> (8 * byt)) & 0xFFu;
        bf16x8 A0 = expand8(b0);
        bf16x8 A1 = expand8(b1);
        union { uint4 u; bf16x8 v; } Bf, Cf;
        Bf.u = eB[(size_t)(kbg0 + kb) * 64 + l];
        Cf.u = cB[(size_t)(kbg0 + kb) * 4 + q];
        aev0 = __builtin_amdgcn_mfma_f32_16x16x32_bf16(A0, Bf.v, aev0, 0, 0, 0);
        ac0  = __builtin_amdgcn_mfma_f32_16x16x32_bf16(A0, Cf.v, ac0,  0, 0, 0);
        aev1 = __builtin_amdgcn_mfma_f32_16x16x32_bf16(A1, Bf.v, aev1, 0, 0, 0);
        ac1  = __builtin_amdgcn_mfma_f32_16x16x32_bf16(A1, Cf.v, ac1,  0, 0, 0);
    }

    // ---- reduce 8 wave-partials (C/D layout: row = q*4+r, col = n;
    // A1's outputs land on block rows 16 + q*4+r)
#pragma unroll
    for (int r = 0; r < 4; ++r) {
        red[w][q * 4 + r][n] = aev0[r];
        red[w][16 + q * 4 + r][n] = aev1[r];
        if (n == 0) {
            red[w][q * 4 + r][16] = ac0[r];
            red[w][16 + q * 4 + r][16] = ac1[r];
        }
    }
    __syncthreads();

    for (int i = tid; i < ROWS_B * NSTAT; i += 512) {
        int row = i / NSTAT, col = i % NSTAT;
        float s = 0.0f;
#pragma unroll
        for (int ww = 0; ww < WAVES; ++ww) s += red[ww][row][col];
        atomicAdd(acc + (size_t)(rowbase + row) * NSTAT + col, s);
    }
}

// out[b] = g_bias + cacc[b] + 0.5 * ||ev[b]||^2
__global__ __launch_bounds__(256) void fm_final(const float* __restrict__ acc,
                                                const float* __restrict__ g_bias,
                                                float* __restrict__ out) {
    int row = blockIdx.x * 256 + threadIdx.x;
    if (row >= B_ROWS) return;
    const float* a = acc + (size_t)row * NSTAT;
    float s = 0.0f;
#pragma unroll
    for (int d = 0; d < D_DIM; ++d) s += a[d] * a[d];
    out[row] = g_bias[0] + a[16] + 0.5f * s;
}

extern "C" void kernel_launch(void* const* d_in, const int* in_sizes, int n_in,
                              void* d_out, int out_size, void* d_ws, size_t ws_size,
                              hipStream_t stream) {
    const int*   x      = (const int*)d_in[0];
    const float* emb_w  = (const float*)d_in[1];
    const float* bias_w = (const float*)d_in[2];
    const float* g_bias = (const float*)d_in[3];
    float*       out    = (float*)d_out;

    // ws: embB 5,120,000 | cB2c 320,000 | acc 69,632
    unsigned short* embB = (unsigned short*)d_ws;
    unsigned short* cB2c = (unsigned short*)((char*)d_ws + (size_t)NKB * 64 * 8 * 2);
    float*          acc  = (float*)((char*)d_ws + (size_t)NKB * 64 * 8 * 2
                                                + (size_t)NKB * 4 * 8 * 2);

    fm_pack<<<dim3(NKB / 4), dim3(256), 0, stream>>>(emb_w, bias_w, embB, cB2c, acc);
    fm_main<<<dim3(ROWBLK, NCHUNK), dim3(512), 0, stream>>>(x, embB, cB2c, acc);
    fm_final<<<dim3((B_ROWS + 255) / 256), dim3(256), 0, stream>>>(acc, g_bias, out);
}